// Round 11
// baseline (148.597 us; speedup 1.0000x reference)
//
#include <hip/hip_runtime.h>
#include <stdint.h>

#define NB 8
#define NS 256
#define ND 1024
#define EPSF 1e-5f
#define BIGF 3.0e38f

typedef __attribute__((ext_vector_type(8))) short short8;
typedef __attribute__((ext_vector_type(4))) float f32x4;

__device__ __forceinline__ unsigned short f2bf(float f) {
  unsigned int u = __float_as_uint(f);
  u = (u + 0x7FFFu + ((u >> 16) & 1u)) >> 16;
  return (unsigned short)u;
}

// ---- k_pre: role A (blk<512) convert+diag; role B (512..1535) LDS-transposed ypfx ----
__global__ __launch_bounds__(256) void k_pre(const float* __restrict__ x,
                                             unsigned short* __restrict__ Xb,
                                             unsigned short* __restrict__ Yb,
                                             float* __restrict__ DGa,
                                             float* __restrict__ IXa) {
  __shared__ struct { float xt[256][9]; float tot[8][33]; } sm;
  int blk = blockIdx.x;
  int tid = threadIdx.x;
  int lane = tid & 63;

  if (blk < 512) {
    int row = blk * 4 + (tid >> 6);
    size_t base = (size_t)row * ND;
    float sq = 0.f;
#pragma unroll
    for (int c = 0; c < 4; ++c) {
      size_t o = base + c * 256 + lane * 4;
      float4 v = *reinterpret_cast<const float4*>(x + o);
      ushort4 ob;
      ob.x = f2bf(v.x); ob.y = f2bf(v.y); ob.z = f2bf(v.z); ob.w = f2bf(v.w);
      *reinterpret_cast<ushort4*>(Xb + o) = ob;
      sq += v.x * v.x + v.y * v.y + v.z * v.z + v.w * v.w;
    }
#pragma unroll
    for (int off = 32; off; off >>= 1) sq += __shfl_xor(sq, off);
    if (lane == 0) {
      DGa[row] = sq;
      IXa[row] = 1.0f / sqrtf(sq);   // inf if 0 -> forces slow path
    }
    return;
  }

  int tile = blk - 512;                // 0..1023
  int b = tile >> 7;
  int d0 = (tile & 127) << 3;
  const float* xs = x + ((size_t)b << 18) + d0;
#pragma unroll
  for (int q = 0; q < 2; ++q) {
    int slot = tid + (q << 8);
    int s = slot >> 1, h = (slot & 1) << 2;
    float4 v = *reinterpret_cast<const float4*>(xs + (size_t)s * ND + h);
    sm.xt[s][h + 0] = v.x;
    sm.xt[s][h + 1] = v.y;
    sm.xt[s][h + 2] = v.z;
    sm.xt[s][h + 3] = v.w;
  }
  __syncthreads();
  int col = tid & 7, ch = tid >> 3;    // 32 chunks x 8 rows each
  float loc[8];
  float run = 0.f;
#pragma unroll
  for (int r = 0; r < 8; ++r) { run += sm.xt[ch * 8 + r][col]; loc[r] = run; }
  sm.tot[col][ch] = run;
  __syncthreads();
#pragma unroll
  for (int off = 1; off < 32; off <<= 1) {
    float tv = (ch >= off) ? sm.tot[col][ch - off] : 0.f;
    __syncthreads();
    sm.tot[col][ch] += tv;
    __syncthreads();
  }
  float excl = sm.tot[col][ch] - run;
#pragma unroll
  for (int r = 0; r < 8; ++r) sm.xt[ch * 8 + r][col] = excl + loc[r];
  __syncthreads();
  unsigned short* yr = Yb + ((size_t)b << 18) + (size_t)tid * ND + d0;
  ushort4 o0, o1;
  o0.x = f2bf(sm.xt[tid][0]); o0.y = f2bf(sm.xt[tid][1]);
  o0.z = f2bf(sm.xt[tid][2]); o0.w = f2bf(sm.xt[tid][3]);
  o1.x = f2bf(sm.xt[tid][4]); o1.y = f2bf(sm.xt[tid][5]);
  o1.z = f2bf(sm.xt[tid][6]); o1.w = f2bf(sm.xt[tid][7]);
  reinterpret_cast<ushort4*>(yr)[0] = o0;
  reinterpret_cast<ushort4*>(yr)[1] = o1;
}

// ---- k_gemmC: C[1+rr, t] = Y_rr . x_t, 2048 16x16 K=1024 wave jobs, direct C write ----
__global__ __launch_bounds__(256) void k_gemmC(const unsigned short* __restrict__ yb,
                                               const unsigned short* __restrict__ xb,
                                               float* __restrict__ C) {
  int job = (blockIdx.x << 2) + (threadIdx.x >> 6);   // 0..2047
  int lane = threadIdx.x & 63;
  int b = job >> 8;
  int mt = (job >> 4) & 15;
  int nt = job & 15;
  const unsigned short* Ab = yb + ((size_t)b << 18) + ((size_t)(mt << 4) << 10);
  const unsigned short* Bb = xb + ((size_t)b << 18) + ((size_t)(nt << 4) << 10);
  int lr = lane & 15;
  int kbase = (lane >> 4) << 3;
  f32x4 ae = {0.f, 0.f, 0.f, 0.f}, ao = {0.f, 0.f, 0.f, 0.f};
#pragma unroll 4
  for (int kk = 0; kk < 1024; kk += 64) {
    const unsigned short* ap = Ab + ((size_t)lr << 10) + kbase + kk;
    const unsigned short* bp = Bb + ((size_t)lr << 10) + kbase + kk;
    short8 a0 = *reinterpret_cast<const short8*>(ap);
    short8 b0 = *reinterpret_cast<const short8*>(bp);
    short8 a1 = *reinterpret_cast<const short8*>(ap + 32);
    short8 b1 = *reinterpret_cast<const short8*>(bp + 32);
    ae = __builtin_amdgcn_mfma_f32_16x16x32_bf16(a0, b0, ae, 0, 0, 0);
    ao = __builtin_amdgcn_mfma_f32_16x16x32_bf16(a1, b1, ao, 0, 0, 0);
  }
  f32x4 acc = ae + ao;
  // C/D layout: col = lane&15, row = (lane>>4)*4 + j   [measured m89]
  float* Cb = C + (size_t)b * 257 * NS;
  int r0 = (mt << 4) + ((lane >> 4) << 2) + 1;   // C row = tile row + 1
  int c0 = (nt << 4) + lr;
#pragma unroll
  for (int j = 0; j < 4; ++j) Cb[(size_t)(r0 + j) * NS + c0] = acc[j];
}

// ---- k_trop: min over t of W-diff / sqrt(ssq); ssq computed block-locally ----
// ssq(i,j) = (P_{j+1}(j+1) - P_{j+1}(i)) - (P_i(j+1) - P_i(i)),  P_r(c) = sum_{t<c} C[r,t]
__global__ __launch_bounds__(256) void k_trop(const float* __restrict__ C,
                                              const float* __restrict__ IXa,
                                              const float* __restrict__ DGa,
                                              float* __restrict__ out) {
  __shared__ float As[64][36];     // As[tt][ii]
  __shared__ float Bs[64][68];     // Bs[tt][jj]
  __shared__ float ssq_t[32][65];  // padded: conflict-free column updates
  __shared__ float wred[4];
  int blk = blockIdx.x;
  int b = blk >> 5;
  int tix = blk & 31;
  int i0 = (tix >> 2) << 5;
  int j0 = (tix & 3) << 6;
  int tid = threadIdx.x;
  int wv = tid >> 6;
  int lane = tid & 63;
  float* outb = out + ((size_t)b << 16);

  if (i0 >= j0 + 63) {             // fully-invalid tile: zero-fill
    float4 z = {0.f, 0.f, 0.f, 0.f};
    float* p = outb + (size_t)(i0 + (tid >> 3)) * NS + j0 + ((tid & 7) << 3);
    reinterpret_cast<float4*>(p)[0] = z;
    reinterpret_cast<float4*>(p)[1] = z;
    return;
  }

  const float* Cb = C + (size_t)b * 257 * NS;
  const float* IXb = IXa + b * NS;

  // ---- ssq prologue, pass 1: rows i (32 rows, 8 per wave) ----
  for (int rr = 0; rr < 8; ++rr) {
    int r = i0 + (wv << 3) + rr;
    const float* Crow = Cb + (size_t)r * NS;
    float carry = 0.f, pii = 0.f;
    int ii = r - i0;
    for (int c0 = 0; c0 < NS; c0 += 64) {
      float v = Crow[c0 + lane];
      float s = v;
#pragma unroll
      for (int off = 1; off < 64; off <<= 1) {
        float n = __shfl_up(s, off);
        if (lane >= off) s += n;
      }
      float excl = carry + s - v;                 // P_r(c0+lane)
      if (c0 == (r & ~63)) pii = __shfl(excl, r & 63);   // P_i(i)
      int c = c0 + lane;
      if (c >= j0 + 1 && c <= j0 + 64) ssq_t[ii][c - j0 - 1] = pii - excl;
      carry += __shfl(s, 63);
    }
    if (j0 == 192 && lane == 0) ssq_t[ii][63] = pii - carry;   // c = 256 edge
  }
  __syncthreads();
  // ---- pass 2: rows j+1 (64 rows, 16 per wave) ----
  for (int rr = 0; rr < 16; ++rr) {
    int jr = j0 + 1 + (wv << 4) + rr;             // 1..256
    int jl = jr - 1 - j0;                          // 0..63
    const float* Crow = Cb + (size_t)jr * NS;
    float carry = 0.f, pd = 0.f, pji = 0.f;
    for (int c0 = 0; c0 < NS; c0 += 64) {
      float v = Crow[c0 + lane];
      float s = v;
#pragma unroll
      for (int off = 1; off < 64; off <<= 1) {
        float n = __shfl_up(s, off);
        if (lane >= off) s += n;
      }
      float excl = carry + s - v;                 // P_jr(c0+lane)
      if (c0 == (i0 & ~63)) pji = __shfl(excl, (i0 & 63) + (lane & 31));  // P_jr(i0+lane&31)
      if (jr < 256 && c0 == (jr & ~63)) pd = __shfl(excl, jr & 63);       // P_jr(jr)
      carry += __shfl(s, 63);
    }
    if (jr == 256) pd = carry;
    if (lane < 32) ssq_t[lane][jl] += pd - pji;
  }
  __syncthreads();

  // ---- wmax for fast-path guard ----
  float wv0 = IXb[tid];
#pragma unroll
  for (int off = 32; off; off >>= 1) wv0 = fmaxf(wv0, __shfl_xor(wv0, off));
  if (lane == 0) wred[wv] = wv0;
  __syncthreads();
  float wmb = fmaxf(fmaxf(wred[0], wred[1]), fmaxf(wred[2], wred[3]));

  int ii0 = (tid >> 4) << 1;     // 0,2,...,30
  int jj0 = (tid & 15) << 2;     // 0,4,...,60
  float acc[8];
#pragma unroll
  for (int k = 0; k < 8; ++k) acc[k] = BIGF;

  int rA = tid >> 4;             // 0..15
  int c4 = (tid & 15) << 2;      // 0..60

  for (int t0 = i0 & ~63; t0 < j0 + 64; t0 += 64) {
    __syncthreads();
    float4 wvx = *reinterpret_cast<const float4*>(IXb + t0 + c4);
#pragma unroll
    for (int p = 0; p < 2; ++p) {      // A: rows i0..i0+31
      int r = i0 + p * 16 + rA;
      float4 v = *reinterpret_cast<const float4*>(Cb + (size_t)r * NS + t0 + c4);
      As[c4 + 0][p * 16 + rA] = v.x * wvx.x;
      As[c4 + 1][p * 16 + rA] = v.y * wvx.y;
      As[c4 + 2][p * 16 + rA] = v.z * wvx.z;
      As[c4 + 3][p * 16 + rA] = v.w * wvx.w;
    }
#pragma unroll
    for (int p = 0; p < 4; ++p) {      // B: rows j0+1..j0+64
      int r = j0 + 1 + p * 16 + rA;
      float4 v = *reinterpret_cast<const float4*>(Cb + (size_t)r * NS + t0 + c4);
      Bs[c4 + 0][p * 16 + rA] = v.x * wvx.x;
      Bs[c4 + 1][p * 16 + rA] = v.y * wvx.y;
      Bs[c4 + 2][p * 16 + rA] = v.z * wvx.z;
      Bs[c4 + 3][p * 16 + rA] = v.w * wvx.w;
    }
    __syncthreads();

    int thA = i0 + ii0 - t0;   // a[k] valid iff tt >= thA + k
    int thB = j0 + jj0 - t0;   // b[l] valid iff tt <= thB + l
    if (thA <= -1 && thB >= 63) {
#pragma unroll 4
      for (int tt = 0; tt < 64; ++tt) {
        float2 a = *reinterpret_cast<const float2*>(&As[tt][ii0]);
        float4 bv = *reinterpret_cast<const float4*>(&Bs[tt][jj0]);
        acc[0] = fminf(acc[0], bv.x - a.x);
        acc[1] = fminf(acc[1], bv.y - a.x);
        acc[2] = fminf(acc[2], bv.z - a.x);
        acc[3] = fminf(acc[3], bv.w - a.x);
        acc[4] = fminf(acc[4], bv.x - a.y);
        acc[5] = fminf(acc[5], bv.y - a.y);
        acc[6] = fminf(acc[6], bv.z - a.y);
        acc[7] = fminf(acc[7], bv.w - a.y);
      }
    } else {
#pragma unroll 4
      for (int tt = 0; tt < 64; ++tt) {
        float2 a = *reinterpret_cast<const float2*>(&As[tt][ii0]);
        float4 bv = *reinterpret_cast<const float4*>(&Bs[tt][jj0]);
        float a0 = (tt >= thA)     ? a.x  : -BIGF;
        float a1 = (tt >= thA + 1) ? a.y  : -BIGF;
        float b0 = (tt <= thB)     ? bv.x :  BIGF;
        float b1 = (tt <= thB + 1) ? bv.y :  BIGF;
        float b2 = (tt <= thB + 2) ? bv.z :  BIGF;
        float b3 = (tt <= thB + 3) ? bv.w :  BIGF;
        acc[0] = fminf(acc[0], b0 - a0);
        acc[1] = fminf(acc[1], b1 - a0);
        acc[2] = fminf(acc[2], b2 - a0);
        acc[3] = fminf(acc[3], b3 - a0);
        acc[4] = fminf(acc[4], b0 - a1);
        acc[5] = fminf(acc[5], b1 - a1);
        acc[6] = fminf(acc[6], b2 - a1);
        acc[7] = fminf(acc[7], b3 - a1);
      }
    }
  }

  const float* DGb = DGa + b * NS;
#pragma unroll
  for (int k = 0; k < 2; ++k) {
    int i = i0 + ii0 + k;
    float o4[4];
#pragma unroll
    for (int l = 0; l < 4; ++l) {
      int j = j0 + jj0 + l;
      float res = 0.f;
      if (i >= 1 && j > i) {
        float ssq = ssq_t[ii0 + k][jj0 + l];
        float sn = sqrtf(fmaxf(ssq, 0.f));
        float win = (float)(j - i + 1);
        if (sn >= EPSF * win * wmb) {
          res = acc[k * 4 + l] / sn;               // fast path: EPS never binds
        } else {
          float mn = sn / win;
          float m = BIGF;
          const float* r2 = Cb + (size_t)(j + 1) * NS;
          const float* r1 = Cb + (size_t)i * NS;
          for (int t = i; t <= j; ++t) {
            float num = r2[t] - r1[t];
            float xn = sqrtf(fmaxf(DGb[t], 0.f));
            float den = fmaxf(mn * xn, EPSF);
            m = fminf(m, num / win / den);
          }
          res = m;
        }
      }
      o4[l] = res;
    }
    float4 st = {o4[0], o4[1], o4[2], o4[3]};
    *reinterpret_cast<float4*>(outb + (size_t)i * NS + j0 + jj0) = st;
  }
}

extern "C" void kernel_launch(void* const* d_in, const int* in_sizes, int n_in,
                              void* d_out, int out_size, void* d_ws, size_t ws_size,
                              hipStream_t stream) {
  (void)in_sizes; (void)n_in; (void)ws_size; (void)out_size;
  const float* x = (const float*)d_in[0];
  float* out = (float*)d_out;
  char* ws = (char*)d_ws;
  unsigned short* Xb = (unsigned short*)(ws);                 //  4,194,304 B
  unsigned short* Yb = (unsigned short*)(ws + 4194304);       //  4,194,304 B
  float* C   = (float*)(ws + 8388608);                        //  2,105,344 B (8 x 257 x 256)
  float* DGa = (float*)(ws + 10493952);                       //  8,192 B
  float* IXa = (float*)(ws + 10502144);                       //  8,192 B

  k_pre<<<1536, 256, 0, stream>>>(x, Xb, Yb, DGa, IXa);
  k_gemmC<<<512, 256, 0, stream>>>(Yb, Xb, C);
  k_trop<<<256, 256, 0, stream>>>(C, IXa, DGa, out);
}

// Round 14
// 110.856 us; speedup vs baseline: 1.3404x; 1.3404x over previous
//
#include <hip/hip_runtime.h>
#include <stdint.h>

#define NB 8
#define NS 256
#define ND 1024
#define EPSF 1e-5f
#define BIGF 3.0e38f

typedef __attribute__((ext_vector_type(8))) short short8;
typedef __attribute__((ext_vector_type(4))) float f32x4;

__device__ __forceinline__ unsigned short f2bf(float f) {
  unsigned int u = __float_as_uint(f);
  u = (u + 0x7FFFu + ((u >> 16) & 1u)) >> 16;
  return (unsigned short)u;
}

// ---- k_pre: role A (blk<512) convert+diag; role B (512..1535) LDS-transposed ypfx ----
__global__ __launch_bounds__(256) void k_pre(const float* __restrict__ x,
                                             unsigned short* __restrict__ Xb,
                                             unsigned short* __restrict__ Yb,
                                             float* __restrict__ DGa,
                                             float* __restrict__ IXa) {
  __shared__ struct { float xt[256][9]; float tot[8][33]; } sm;
  int blk = blockIdx.x;
  int tid = threadIdx.x;
  int lane = tid & 63;

  if (blk < 512) {
    int row = blk * 4 + (tid >> 6);
    size_t base = (size_t)row * ND;
    float sq = 0.f;
#pragma unroll
    for (int c = 0; c < 4; ++c) {
      size_t o = base + c * 256 + lane * 4;
      float4 v = *reinterpret_cast<const float4*>(x + o);
      ushort4 ob;
      ob.x = f2bf(v.x); ob.y = f2bf(v.y); ob.z = f2bf(v.z); ob.w = f2bf(v.w);
      *reinterpret_cast<ushort4*>(Xb + o) = ob;
      sq += v.x * v.x + v.y * v.y + v.z * v.z + v.w * v.w;
    }
#pragma unroll
    for (int off = 32; off; off >>= 1) sq += __shfl_xor(sq, off);
    if (lane == 0) {
      DGa[row] = sq;
      IXa[row] = 1.0f / sqrtf(sq);   // inf if 0 -> forces slow path
    }
    return;
  }

  int tile = blk - 512;                // 0..1023
  int b = tile >> 7;
  int d0 = (tile & 127) << 3;
  const float* xs = x + ((size_t)b << 18) + d0;
#pragma unroll
  for (int q = 0; q < 2; ++q) {
    int slot = tid + (q << 8);
    int s = slot >> 1, h = (slot & 1) << 2;
    float4 v = *reinterpret_cast<const float4*>(xs + (size_t)s * ND + h);
    sm.xt[s][h + 0] = v.x;
    sm.xt[s][h + 1] = v.y;
    sm.xt[s][h + 2] = v.z;
    sm.xt[s][h + 3] = v.w;
  }
  __syncthreads();
  int col = tid & 7, ch = tid >> 3;    // 32 chunks x 8 rows each
  float loc[8];
  float run = 0.f;
#pragma unroll
  for (int r = 0; r < 8; ++r) { run += sm.xt[ch * 8 + r][col]; loc[r] = run; }
  sm.tot[col][ch] = run;
  __syncthreads();
#pragma unroll
  for (int off = 1; off < 32; off <<= 1) {
    float tv = (ch >= off) ? sm.tot[col][ch - off] : 0.f;
    __syncthreads();
    sm.tot[col][ch] += tv;
    __syncthreads();
  }
  float excl = sm.tot[col][ch] - run;
#pragma unroll
  for (int r = 0; r < 8; ++r) sm.xt[ch * 8 + r][col] = excl + loc[r];
  __syncthreads();
  unsigned short* yr = Yb + ((size_t)b << 18) + (size_t)tid * ND + d0;
  ushort4 o0, o1;
  o0.x = f2bf(sm.xt[tid][0]); o0.y = f2bf(sm.xt[tid][1]);
  o0.z = f2bf(sm.xt[tid][2]); o0.w = f2bf(sm.xt[tid][3]);
  o1.x = f2bf(sm.xt[tid][4]); o1.y = f2bf(sm.xt[tid][5]);
  o1.z = f2bf(sm.xt[tid][6]); o1.w = f2bf(sm.xt[tid][7]);
  reinterpret_cast<ushort4*>(yr)[0] = o0;
  reinterpret_cast<ushort4*>(yr)[1] = o1;
}

// ---- k_gemmC: C[1+rr, t] = Y_rr . x_t, 2048 16x16 K=1024 wave jobs, direct C write ----
__global__ __launch_bounds__(256) void k_gemmC(const unsigned short* __restrict__ yb,
                                               const unsigned short* __restrict__ xb,
                                               float* __restrict__ C) {
  int job = (blockIdx.x << 2) + (threadIdx.x >> 6);   // 0..2047
  int lane = threadIdx.x & 63;
  int b = job >> 8;
  int mt = (job >> 4) & 15;
  int nt = job & 15;
  const unsigned short* Ab = yb + ((size_t)b << 18) + ((size_t)(mt << 4) << 10);
  const unsigned short* Bb = xb + ((size_t)b << 18) + ((size_t)(nt << 4) << 10);
  int lr = lane & 15;
  int kbase = (lane >> 4) << 3;
  f32x4 ae = {0.f, 0.f, 0.f, 0.f}, ao = {0.f, 0.f, 0.f, 0.f};
#pragma unroll 4
  for (int kk = 0; kk < 1024; kk += 64) {
    const unsigned short* ap = Ab + ((size_t)lr << 10) + kbase + kk;
    const unsigned short* bp = Bb + ((size_t)lr << 10) + kbase + kk;
    short8 a0 = *reinterpret_cast<const short8*>(ap);
    short8 b0 = *reinterpret_cast<const short8*>(bp);
    short8 a1 = *reinterpret_cast<const short8*>(ap + 32);
    short8 b1 = *reinterpret_cast<const short8*>(bp + 32);
    ae = __builtin_amdgcn_mfma_f32_16x16x32_bf16(a0, b0, ae, 0, 0, 0);
    ao = __builtin_amdgcn_mfma_f32_16x16x32_bf16(a1, b1, ao, 0, 0, 0);
  }
  f32x4 acc = ae + ao;
  // C/D layout: col = lane&15, row = (lane>>4)*4 + j   [measured m89]
  float* Cb = C + (size_t)b * 257 * NS;
  int r0 = (mt << 4) + ((lane >> 4) << 2) + 1;   // C row = tile row + 1
  int c0 = (nt << 4) + lr;
#pragma unroll
  for (int j = 0; j < 4; ++j) Cb[(size_t)(r0 + j) * NS + c0] = acc[j];
}

// ---- k_trop: min_t (C[j+1,t]-C[i,t])*w_t / sqrt(ssq); ssq fused into the min loop ----
// ssq(i,j) = sum_{t in [i..j]} (C[j+1,t] - C[i,t])  -- same mask, same staged data
__global__ __launch_bounds__(256) void k_trop(const float* __restrict__ C,
                                              const float* __restrict__ IXa,
                                              const float* __restrict__ DGa,
                                              float* __restrict__ out) {
  __shared__ float As[64][36];     // raw C rows i0..i0+31 (As[tt][ii])
  __shared__ float Bs[64][68];     // raw C rows j0+1..j0+64 (Bs[tt][jj])
  __shared__ float wls[64];        // inv_xnorm[t0+tt]
  __shared__ float wred[4];
  int blk = blockIdx.x;
  int b = blk >> 5;
  int tix = blk & 31;
  int i0 = (tix >> 2) << 5;
  int j0 = (tix & 3) << 6;
  int tid = threadIdx.x;
  int wv = tid >> 6;
  int lane = tid & 63;
  float* outb = out + ((size_t)b << 16);

  if (i0 >= j0 + 63) {             // fully-invalid tile: zero-fill
    float4 z = {0.f, 0.f, 0.f, 0.f};
    float* p = outb + (size_t)(i0 + (tid >> 3)) * NS + j0 + ((tid & 7) << 3);
    reinterpret_cast<float4*>(p)[0] = z;
    reinterpret_cast<float4*>(p)[1] = z;
    return;
  }

  const float* Cb = C + (size_t)b * 257 * NS;
  const float* IXb = IXa + b * NS;

  // wmax for fast-path guard
  float wv0 = IXb[tid];
#pragma unroll
  for (int off = 32; off; off >>= 1) wv0 = fmaxf(wv0, __shfl_xor(wv0, off));
  if (lane == 0) wred[wv] = wv0;
  __syncthreads();
  float wmb = fmaxf(fmaxf(wred[0], wred[1]), fmaxf(wred[2], wred[3]));

  int ii0 = (tid >> 4) << 1;     // 0,2,...,30
  int jj0 = (tid & 15) << 2;     // 0,4,...,60
  float acc[8], sq[8];
#pragma unroll
  for (int k = 0; k < 8; ++k) { acc[k] = BIGF; sq[k] = 0.f; }

  int rA = tid >> 4;             // 0..15
  int c4 = (tid & 15) << 2;      // 0..60

  for (int t0 = i0 & ~63; t0 < j0 + 64; t0 += 64) {
    __syncthreads();
    if (tid < 16) {
      float4 w = *reinterpret_cast<const float4*>(IXb + t0 + (tid << 2));
      wls[(tid << 2) + 0] = w.x;
      wls[(tid << 2) + 1] = w.y;
      wls[(tid << 2) + 2] = w.z;
      wls[(tid << 2) + 3] = w.w;
    }
#pragma unroll
    for (int p = 0; p < 2; ++p) {      // A: raw rows i0..i0+31
      int r = i0 + p * 16 + rA;
      float4 v = *reinterpret_cast<const float4*>(Cb + (size_t)r * NS + t0 + c4);
      As[c4 + 0][p * 16 + rA] = v.x;
      As[c4 + 1][p * 16 + rA] = v.y;
      As[c4 + 2][p * 16 + rA] = v.z;
      As[c4 + 3][p * 16 + rA] = v.w;
    }
#pragma unroll
    for (int p = 0; p < 4; ++p) {      // B: raw rows j0+1..j0+64
      int r = j0 + 1 + p * 16 + rA;
      float4 v = *reinterpret_cast<const float4*>(Cb + (size_t)r * NS + t0 + c4);
      Bs[c4 + 0][p * 16 + rA] = v.x;
      Bs[c4 + 1][p * 16 + rA] = v.y;
      Bs[c4 + 2][p * 16 + rA] = v.z;
      Bs[c4 + 3][p * 16 + rA] = v.w;
    }
    __syncthreads();

    int thA = i0 + ii0 - t0;   // a[k] valid iff tt >= thA + k
    int thB = j0 + jj0 - t0;   // b[l] valid iff tt <= thB + l
    if (thA <= -1 && thB >= 63) {      // interior: all tt valid for all 8 cells
#pragma unroll 4
      for (int tt = 0; tt < 64; ++tt) {
        float wt = wls[tt];
        float2 a = *reinterpret_cast<const float2*>(&As[tt][ii0]);
        float4 bv = *reinterpret_cast<const float4*>(&Bs[tt][jj0]);
        float d0 = bv.x - a.x, d1 = bv.y - a.x, d2 = bv.z - a.x, d3 = bv.w - a.x;
        float d4 = bv.x - a.y, d5 = bv.y - a.y, d6 = bv.z - a.y, d7 = bv.w - a.y;
        acc[0] = fminf(acc[0], d0 * wt); sq[0] += d0;
        acc[1] = fminf(acc[1], d1 * wt); sq[1] += d1;
        acc[2] = fminf(acc[2], d2 * wt); sq[2] += d2;
        acc[3] = fminf(acc[3], d3 * wt); sq[3] += d3;
        acc[4] = fminf(acc[4], d4 * wt); sq[4] += d4;
        acc[5] = fminf(acc[5], d5 * wt); sq[5] += d5;
        acc[6] = fminf(acc[6], d6 * wt); sq[6] += d6;
        acc[7] = fminf(acc[7], d7 * wt); sq[7] += d7;
      }
    } else {
#pragma unroll 4
      for (int tt = 0; tt < 64; ++tt) {
        float wt = wls[tt];
        float2 a = *reinterpret_cast<const float2*>(&As[tt][ii0]);
        float4 bv = *reinterpret_cast<const float4*>(&Bs[tt][jj0]);
        bool va0 = tt >= thA, va1 = tt >= thA + 1;
        bool vb0 = tt <= thB, vb1 = tt <= thB + 1, vb2 = tt <= thB + 2, vb3 = tt <= thB + 3;
        float d0 = bv.x - a.x, d1 = bv.y - a.x, d2 = bv.z - a.x, d3 = bv.w - a.x;
        float d4 = bv.x - a.y, d5 = bv.y - a.y, d6 = bv.z - a.y, d7 = bv.w - a.y;
        acc[0] = fminf(acc[0], (va0 && vb0) ? d0 * wt : BIGF); sq[0] += (va0 && vb0) ? d0 : 0.f;
        acc[1] = fminf(acc[1], (va0 && vb1) ? d1 * wt : BIGF); sq[1] += (va0 && vb1) ? d1 : 0.f;
        acc[2] = fminf(acc[2], (va0 && vb2) ? d2 * wt : BIGF); sq[2] += (va0 && vb2) ? d2 : 0.f;
        acc[3] = fminf(acc[3], (va0 && vb3) ? d3 * wt : BIGF); sq[3] += (va0 && vb3) ? d3 : 0.f;
        acc[4] = fminf(acc[4], (va1 && vb0) ? d4 * wt : BIGF); sq[4] += (va1 && vb0) ? d4 : 0.f;
        acc[5] = fminf(acc[5], (va1 && vb1) ? d5 * wt : BIGF); sq[5] += (va1 && vb1) ? d5 : 0.f;
        acc[6] = fminf(acc[6], (va1 && vb2) ? d6 * wt : BIGF); sq[6] += (va1 && vb2) ? d6 : 0.f;
        acc[7] = fminf(acc[7], (va1 && vb3) ? d7 * wt : BIGF); sq[7] += (va1 && vb3) ? d7 : 0.f;
      }
    }
  }

  const float* DGb = DGa + b * NS;
#pragma unroll
  for (int k = 0; k < 2; ++k) {
    int i = i0 + ii0 + k;
    float o4[4];
#pragma unroll
    for (int l = 0; l < 4; ++l) {
      int j = j0 + jj0 + l;
      float res = 0.f;
      if (i >= 1 && j > i) {
        float ssq = sq[k * 4 + l];
        float sn = sqrtf(fmaxf(ssq, 0.f));
        float win = (float)(j - i + 1);
        if (sn >= EPSF * win * wmb) {
          res = acc[k * 4 + l] / sn;               // fast path: EPS never binds
        } else {
          float mn = sn / win;
          float m = BIGF;
          const float* r2 = Cb + (size_t)(j + 1) * NS;
          const float* r1 = Cb + (size_t)i * NS;
          for (int t = i; t <= j; ++t) {
            float num = r2[t] - r1[t];
            float xn = sqrtf(fmaxf(DGb[t], 0.f));
            float den = fmaxf(mn * xn, EPSF);
            m = fminf(m, num / win / den);
          }
          res = m;
        }
      }
      o4[l] = res;
    }
    float4 st = {o4[0], o4[1], o4[2], o4[3]};
    *reinterpret_cast<float4*>(outb + (size_t)i * NS + j0 + jj0) = st;
  }
}

extern "C" void kernel_launch(void* const* d_in, const int* in_sizes, int n_in,
                              void* d_out, int out_size, void* d_ws, size_t ws_size,
                              hipStream_t stream) {
  (void)in_sizes; (void)n_in; (void)ws_size; (void)out_size;
  const float* x = (const float*)d_in[0];
  float* out = (float*)d_out;
  char* ws = (char*)d_ws;
  unsigned short* Xb = (unsigned short*)(ws);                 //  4,194,304 B
  unsigned short* Yb = (unsigned short*)(ws + 4194304);       //  4,194,304 B
  float* C   = (float*)(ws + 8388608);                        //  2,105,344 B (8 x 257 x 256)
  float* DGa = (float*)(ws + 10493952);                       //  8,192 B
  float* IXa = (float*)(ws + 10502144);                       //  8,192 B

  k_pre<<<1536, 256, 0, stream>>>(x, Xb, Yb, DGa, IXa);
  k_gemmC<<<512, 256, 0, stream>>>(Yb, Xb, C);
  k_trop<<<256, 256, 0, stream>>>(C, IXa, DGa, out);
}